// Round 4
// baseline (404.446 us; speedup 1.0000x reference)
//
#include <hip/hip_runtime.h>
#include <cstdint>

typedef unsigned long long u64;
typedef unsigned int u32;

#define B_ 4
#define N_ 3600
#define C_ 16
#define NW_ 57        // ceil(N/64) words of adjacency/valid bitmask
#define NWP_ 64       // padded row stride (u64 words) -> unguarded 64-lane loads
#define NPAD_ 3648    // NW_*64
#define RPW_ 4        // rows per wave
#define RPB_ 16       // rows per block (4 waves)

// ---------------------------------------------------------------------------
// K1: pure adjacency-bitmask kernel. 4 rows/wave, 16 rows/block. Each row's
// 57 words accumulate in per-lane registers (lane t holds word t) -> one
// contiguous 512B store per row. rowsum[i] bit t = (word t != 0), for the
// sparse adjacency-con check in k_select.
//
// Exact division-free IoU test:
//   round_f32(inter/denom) >= 0.4f  <=>  inter > (0.4f - 2^-26)*denom in f64
//   (exact: 26-bit * 24-bit mantissa product; midpoint ties round-to-even to
//   prev(0.4f) < 0.4f -> false, matching strict '>'). denom==0 => inter==0
//   => false, matching 0/0=NaN >= 0.4 false. Zero-padded boxes => false.
// ---------------------------------------------------------------------------
__global__ __launch_bounds__(256) void k_adj(const float* __restrict__ boxes,
                                             u64* __restrict__ adj,
                                             u64* __restrict__ rowsum) {
#pragma clang fp contract(off)
    __shared__ float4 sbox[NPAD_];   // (x1,y1,x2,y2)
    const int tid  = threadIdx.x;
    const int lane = tid & 63;
    const int wv   = tid >> 6;
    const int g    = blockIdx.x;                 // 0 .. B*N/16-1
    const int b    = g / (N_ / RPB_);
    const int r0   = (g % (N_ / RPB_)) * RPB_ + wv * RPW_;
    const size_t bN = (size_t)b * N_;

    for (int j = tid; j < NPAD_; j += 256) {
        float x1 = 0.f, y1 = 0.f, x2 = 0.f, y2 = 0.f;
        if (j < N_) {
            const float4 bx = reinterpret_cast<const float4*>(boxes)[bN + j];
            x1 = bx.x - bx.z * 0.5f;   // cx - w/2
            y1 = bx.y - bx.w * 0.5f;
            x2 = x1 + bx.z;            // x1 + w  (exact reference op order)
            y2 = y1 + bx.w;
        }
        sbox[j] = make_float4(x1, y1, x2, y2);
    }
    __syncthreads();

    float4 bi[RPW_];
    float  ai[RPW_];
#pragma unroll
    for (int r = 0; r < RPW_; ++r) {
        bi[r] = sbox[r0 + r];
        ai[r] = (bi[r].z - bi[r].x) * (bi[r].w - bi[r].y);
    }
    const double MID = (double)0.4f - 0x1p-26;   // exact

    u64 row[RPW_];
#pragma unroll
    for (int r = 0; r < RPW_; ++r) row[r] = 0ull;

    for (int t = 0; t < NW_; ++t) {
        const int    j   = t * 64 + lane;
        const float4 bj  = sbox[j];
        const float  ajr = (bj.z - bj.x) * (bj.w - bj.y);
#pragma unroll
        for (int r = 0; r < RPW_; ++r) {
            const float ltx = fmaxf(bi[r].x, bj.x);
            const float lty = fmaxf(bi[r].y, bj.y);
            const float rbx = fminf(bi[r].z, bj.z);
            const float rby = fminf(bi[r].w, bj.w);
            const float whx = fmaxf(rbx - ltx, 0.0f);
            const float why = fmaxf(rby - lty, 0.0f);
            const float inter = whx * why;
            const float denom = (ai[r] + ajr) - inter;
            const int pred = ((double)inter > MID * (double)denom) && (j != r0 + r);
            const u64 m = __ballot(pred);
            if (lane == t) row[r] = m;     // 2x v_cndmask, no LDS
        }
    }

#pragma unroll
    for (int r = 0; r < RPW_; ++r) {
        const int i = r0 + r;
        adj[(bN + i) * NWP_ + lane] = row[r];          // lanes >= NW_ hold 0
        const u64 summ = __ballot(row[r] != 0ull);
        if (lane == 0) rowsum[bN + i] = summ;
    }
}

// ---------------------------------------------------------------------------
// K2: fused valid0 -> sparse adjcon check -> sort -> greedy NMS -> output,
// one 256-thread block per (b,c).
//
// valid0 = (p>=conf) & (p>=adj_con) & (p>=con_i)
//        = (p>=conf) & (p>=0) & (p>=con_i) & (forall adjacent j: p>=con_j).
// Pre-candidates (first three terms) are compacted, then the quantifier is
// checked per pre-candidate via rowsum (sparse rows => ~1-3 loads each).
// Failed pre-candidates are excluded outright: not in valid0 => can neither
// survive nor suppress (greedy only clears bits). pvm (pre-candidate ballots,
// a superset of valid0) is a safe suppression-state init: bits of failed
// entries are never consulted.
// ---------------------------------------------------------------------------
__global__ __launch_bounds__(256) void k_select(const float* __restrict__ pro,
                                                const float* __restrict__ con,
                                                const float* __restrict__ conf,
                                                const u64* __restrict__ adj,
                                                const u64* __restrict__ rowsum,
                                                const float* __restrict__ boxes,
                                                const float* __restrict__ scales,
                                                float* __restrict__ out) {
#pragma clang fp contract(off)
    __shared__ u64 keys[4096];          // (~score_bits << 32) | idx  (asc sort)
    __shared__ float spro[NPAD_];
    __shared__ float scon[NPAD_];
    __shared__ u32 cand[NPAD_];         // pre-candidate indices (unordered)
    __shared__ u32 slist[NPAD_];        // survivor indices, greedy order
    __shared__ u64 pvm[NW_];
    __shared__ u32 s_pre, s_T, s_S;
    const int tid  = threadIdx.x;
    const int lane = tid & 63;
    const int wv   = tid >> 6;
    const int bc   = blockIdx.x;
    const int b    = bc / C_, c = bc % C_;
    const size_t bN = (size_t)b * N_;
    const float cf = conf[c];

    if (tid == 0) { s_pre = 0; s_T = 0; }
    __syncthreads();

    // --- phase 1a: pre-candidates + stage pro/con slices in LDS ---
    for (int t = wv; t < NW_; t += 4) {
        const int i = t * 64 + lane;
        int pred = 0;
        float p = 0.f, cn = 0.f;
        if (i < N_) {
            const size_t off = (bN + i) * C_ + c;
            p  = pro[off];
            cn = con[off];
            pred = (p >= cf) && (p >= cn) && (p >= 0.0f);
        }
        spro[t * 64 + lane] = p;
        scon[t * 64 + lane] = cn;
        const u64 bm = __ballot(pred);
        if (lane == 0) pvm[t] = bm;
        u32 base = 0;
        if (lane == 0 && bm) base = atomicAdd(&s_pre, (u32)__popcll(bm));
        base = (u32)__shfl((int)base, 0);
        if (pred) cand[base + (u32)__popcll(bm & ((1ull << lane) - 1ull))] = (u32)i;
    }
    __syncthreads();

    // --- phase 1c: sparse adjacency-con check, keyed compaction ---
    const int preT = (int)s_pre;
    for (int s = tid; s < preT; s += 256) {
        const int   i = (int)cand[s];
        const float p = spro[i];
        u64 sm = rowsum[bN + i];
        bool ok = true;
        while (sm && ok) {
            const int t = __builtin_ctzll(sm); sm &= sm - 1;
            u64 w = adj[(bN + i) * NWP_ + t];
            while (w) {
                const int j = __builtin_ctzll(w); w &= w - 1;
                if (!(p >= scon[t * 64 + j])) { ok = false; break; }
            }
        }
        if (ok) {
            const u32 bits = __float_as_uint(p);
            const u32 mk = bits ^ ((bits >> 31) ? 0xFFFFFFFFu : 0x80000000u);
            const u32 pos = atomicAdd(&s_T, 1u);
            keys[pos] = (((u64)(~mk)) << 32) | (u32)i;
        }
    }
    __syncthreads();

    const int T = (int)s_T;
    int P = 2;
    while (P < T) P <<= 1;              // P <= 4096
    for (int x = T + tid; x < P; x += 256) keys[x] = ~0ull;
    __syncthreads();

    // --- phase 2: bitonic sort (ascending => score desc, idx asc) ---
    for (int k = 2; k <= P; k <<= 1) {
        for (int j = k >> 1; j > 0; j >>= 1) {
            for (int t = tid; t < P; t += 256) {
                const int ixj = t ^ j;
                if (ixj > t) {
                    const u64 a = keys[t], bb = keys[ixj];
                    const bool up = ((t & k) == 0);
                    if ((a > bb) == up) { keys[t] = bb; keys[ixj] = a; }
                }
            }
            __syncthreads();
        }
    }

    // --- phase 3: greedy suppression (wave 0, 16-deep register pipeline) ---
    if (wv == 0) {
        const u32* keys32 = (const u32*)keys;   // low word of keys[i] = idx
        u64 myword = (lane < NW_) ? pvm[lane] : 0ull;
        u32 ordv = keys32[2 * lane];            // idx for candidates [0,64)
        u64 rowp[16];
        u32 idxp[16];
#pragma unroll
        for (int d = 0; d < 16; ++d) {
            const u32 idxn = (d < T) ? (u32)__builtin_amdgcn_readlane((int)ordv, d) : 0u;
            idxp[d] = idxn;
            rowp[d] = adj[(bN + idxn) * NWP_ + lane];
        }
        u32 S = 0;
        for (int k0 = 0; k0 < T; k0 += 16) {
#pragma unroll
            for (int d = 0; d < 16; ++d) {
                const int k = k0 + d;
                const u32 idx = idxp[d];
                const u64 row = rowp[d];        // load issued 16 iters ago
                // prefetch candidate k+16
                const int kn = k + 16;
                if ((kn & 63) == 0) ordv = keys32[2 * (kn + lane)];
                const u32 idxn = (kn < T) ? (u32)__builtin_amdgcn_readlane((int)ordv, kn & 63) : 0u;
                idxp[d] = idxn;
                rowp[d] = adj[(bN + idxn) * NWP_ + lane];
                // bit test via scalar readlane (wave-uniform, no LDS latency)
                const int  w   = (int)(idx >> 6);
                const u32  lo  = (u32)__builtin_amdgcn_readlane((int)(u32)myword, w);
                const u32  hi  = (u32)__builtin_amdgcn_readlane((int)(u32)(myword >> 32), w);
                const u32  sel = (idx & 32) ? hi : lo;
                u32 bit = (sel >> (idx & 31)) & 1u;
                bit &= (u32)(k < T);
                const u64 bm = bit ? ~0ull : 0ull;
                myword &= ~(row & bm);
                if (lane == 0) slist[bit ? S : (NPAD_ - 1)] = idx;
                S += bit;
            }
        }
        if (lane == 0) s_S = S;
    }
    __syncthreads();

    // --- phase 4: parallel output of survivors in greedy order ---
    const int S = (int)s_S;
    const float s = scales[b];
    for (int r = tid; r < S; r += 256) {
        const int idx = (int)slist[r];
        const float4 bx = reinterpret_cast<const float4*>(boxes)[bN + idx];
        const float scx = bx.x * s, scy = bx.y * s, sw = bx.z * s, sh = bx.w * s;
        float* o = out + ((size_t)bc * N_ + r) * 5;
        o[0] = scx - 0.5f * sw;
        o[1] = scy - 0.5f * sh;
        o[2] = scx + 0.5f * sw;
        o[3] = scy + 0.5f * sh;
        o[4] = spro[idx];
        out[(size_t)B_ * C_ * N_ * 5 + (size_t)bc * N_ + r] = 1.0f;
    }
}

// ---------------------------------------------------------------------------
extern "C" void kernel_launch(void* const* d_in, const int* in_sizes, int n_in,
                              void* d_out, int out_size, void* d_ws, size_t ws_size,
                              hipStream_t stream) {
    const float* pro    = (const float*)d_in[0];   // (B,N,C)
    const float* con    = (const float*)d_in[1];   // (B,N,C)
    const float* boxes  = (const float*)d_in[2];   // (B,N,4)
    const float* scales = (const float*)d_in[3];   // (B,)
    const float* conf   = (const float*)d_in[4];   // (C,)

    char* ws = (char*)d_ws;
    u64* adj = (u64*)ws;                                   // B*N*NWP u64 (7.37 MB)
    size_t off = (size_t)B_ * N_ * NWP_ * sizeof(u64);
    u64* rowsum = (u64*)(ws + off);                        // B*N u64    (115 KB)

    hipMemsetAsync(d_out, 0, (size_t)out_size * sizeof(float), stream);
    k_adj   <<<B_ * N_ / RPB_, 256, 0, stream>>>(boxes, adj, rowsum);
    k_select<<<B_ * C_,        256, 0, stream>>>(pro, con, conf, adj, rowsum,
                                                 boxes, scales, (float*)d_out);
}